// Round 1
// 748.329 us; speedup vs baseline: 1.1903x; 1.1903x over previous
//
#include <hip/hip_runtime.h>

// Problem constants: T=32768 tokens, H=2048 hidden, I=768 intermediate
#define T_TOK 32768
#define H_DIM 2048
#define I_DIM 768
#define N1_DIM 1536   // 2*I

typedef unsigned short ushort_t;
typedef __attribute__((ext_vector_type(8))) short  short8;   // 8 bf16 = 4 VGPRs (MFMA A/B frag)
typedef __attribute__((ext_vector_type(4))) float  floatx4;  // MFMA C/D frag

// ---- bf16 helpers (raw-bit, RNE) ----
__device__ __forceinline__ ushort_t f2bf(float f) {
    union { float f; unsigned u; } v; v.f = f;
    unsigned u = v.u;
    unsigned r = (u + 0x7fffu + ((u >> 16) & 1u)) >> 16;
    return (ushort_t)r;
}

// ---- async global->LDS, 16B per lane (dest = wave-uniform base + lane*16) ----
typedef __attribute__((address_space(1))) const void gq_t;
typedef __attribute__((address_space(3))) void lq_t;
__device__ __forceinline__ void gld_lds16(const void* g, void* l) {
    __builtin_amdgcn_global_load_lds((gq_t*)g, (lq_t*)l, 16, 0, 0);
}

// =====================================================================
// cast fp32 -> bf16, 8 elems/thread (grid*256*8 == n exactly)
// =====================================================================
__global__ __launch_bounds__(256) void cast_f32_bf16_k(
    const float* __restrict__ in, ushort_t* __restrict__ out)
{
    size_t i = ((size_t)blockIdx.x * 256 + threadIdx.x) * 8;
    const float4 a = *(const float4*)(in + i);
    const float4 b = *(const float4*)(in + i + 4);
    short8 o;
    o[0] = (short)f2bf(a.x); o[1] = (short)f2bf(a.y);
    o[2] = (short)f2bf(a.z); o[3] = (short)f2bf(a.w);
    o[4] = (short)f2bf(b.x); o[5] = (short)f2bf(b.y);
    o[6] = (short)f2bf(b.z); o[7] = (short)f2bf(b.w);
    *(short8*)(out + i) = o;
}

// =====================================================================
// gate/up pairing permutation for wgu_t rows:
//   source col c (c<768: gate c ; c>=768: up c-768) -> out row
//   pair group of 32 rows = [16 gate cols | 16 up cols] for the same ci range.
// =====================================================================
__device__ __forceinline__ int gu_perm(int c) {
    const int t  = (c >= I_DIM) ? 1 : 0;
    const int cc = c - t * I_DIM;
    return ((cc >> 4) << 5) + (t << 4) + (cc & 15);
}

// =====================================================================
// transpose + cast: in fp32 [R][C] -> out bf16 [perm(C)][R]  (R,C mult of 32)
// =====================================================================
template <bool PERM>
__global__ __launch_bounds__(256) void transpose_cast_k(
    const float* __restrict__ in, ushort_t* __restrict__ out, int R, int C)
{
    __shared__ float tile[32][33];
    const int c0 = blockIdx.x * 32;
    const int r0 = blockIdx.y * 32;
    const int tx = threadIdx.x;   // 0..31
    const int ty = threadIdx.y;   // 0..7
#pragma unroll
    for (int dy = 0; dy < 32; dy += 8)
        tile[ty + dy][tx] = in[(size_t)(r0 + ty + dy) * C + (c0 + tx)];
    __syncthreads();
#pragma unroll
    for (int dy = 0; dy < 32; dy += 8) {
        const int c = c0 + ty + dy;
        const int orow = PERM ? gu_perm(c) : c;
        out[(size_t)orow * R + (r0 + tx)] = f2bf(tile[tx][ty + dy]);
    }
}

// =====================================================================
// bf16 GEMM, C = A @ Bt^T — 256x256 tile, BK=64, 512 thr (8 waves, 2Mx4N),
// double-buffered 128 KiB LDS, 4-phase/K-tile schedule with counted vmcnt
// (T3+T4) + setprio around MFMA clusters (T5) + bijective XCD swizzle (T1).
//
// LDS layout (ushort idx): As[buf][khalf][256 rows][32 k] at 0,
//                          Bs[...] at +32768.  Row stride 64 B -> frag
// ds_read_b128 spreads 8 distinct addrs per 4-bank group (conflict-free,
// same distribution the previous kernel measured at 0 conflicts).
// Staging: linear global_load_lds, 16B/lane; one "half" = 256 rows x 32 k
// of one matrix = 2 issues/thread.  8 issues per K-tile, spread 2/phase.
// vmcnt(4) at end of P1 and P3 always leaves the 4 newest loads in flight.
//
// EPI==0: fp32 C store.  EPI==1: paired gate/up -> x = silu(g)*u, bf16.
// =====================================================================
#define GB    __builtin_amdgcn_s_barrier()
#define SB0   __builtin_amdgcn_sched_barrier(0)
#define LGKM0 asm volatile("s_waitcnt lgkmcnt(0)" ::: "memory")
#define VMW(N) asm volatile("s_waitcnt vmcnt(" #N ")" ::: "memory")

template <int EPI>
__global__ __launch_bounds__(512, 2) void gemm_bt8(
    const ushort_t* __restrict__ A,
    const ushort_t* __restrict__ Bt,
    void* __restrict__ Cv,
    int lda, int ldb, int ldc, int K)
{
    __shared__ __align__(16) ushort_t lds[65536];   // 128 KiB

    const int tid  = threadIdx.x;
    const int lane = tid & 63;
    const int wave = tid >> 6;
    const int wm   = (wave >> 2) * 128;   // wave origin rows within tile
    const int wn   = (wave & 3) * 64;     // wave origin cols within tile
    const int s    = lane & 15;
    const int q    = lane >> 4;

    // bijective XCD swizzle (gridDim.x % 8 == 0 for both GEMMs), m-fastest
    const int nwg = gridDim.x;
    const int cpx = nwg >> 3;
    const int wg  = blockIdx.x;
    const int swz = (wg & 7) * cpx + (wg >> 3);
    const int m0  = (swz & 127) * 256;    // T/256 = 128 row-blocks (both GEMMs)
    const int n0  = (swz >> 7) * 256;

    // staging: lane covers row = c*128 + wave*16 + (lane>>2), kword = lane&3
    const int srow = wave * 16 + (lane >> 2);
    const int scol = (lane & 3) * 8;
    const ushort_t* Ab = A  + (size_t)(m0 + srow) * lda + scol;
    const ushort_t* Bb = Bt + (size_t)(n0 + srow) * ldb + scol;
    ushort_t* ldsA = &lds[wave * 512];            // wave-uniform dest base
    ushort_t* ldsB = &lds[32768 + wave * 512];

#define STAGE_A(kt, h, c, b) gld_lds16(Ab + (size_t)((c)*128) * lda + (kt) + (h)*32, \
                                       ldsA + ((b)*2 + (h)) * 8192 + (c)*4096)
#define STAGE_B(kt, h, c, b) gld_lds16(Bb + (size_t)((c)*128) * ldb + (kt) + (h)*32, \
                                       ldsB + ((b)*2 + (h)) * 8192 + (c)*4096)

    const int arow = wm + s;
    const int brow = wn + s;
#define LDA4(b, ks, mh, av) { _Pragma("unroll") for (int ii = 0; ii < 4; ++ii) \
    av[ii] = *(const short8*)&lds[((b)*2 + (ks)) * 8192 + (arow + (mh)*64 + ii*16) * 32 + q*8]; }
#define LDB4(b, ks, bv) { _Pragma("unroll") for (int jj = 0; jj < 4; ++jj) \
    bv[jj] = *(const short8*)&lds[32768 + ((b)*2 + (ks)) * 8192 + (brow + jj*16) * 32 + q*8]; }
#define MFMA16(mh, av, bv) { _Pragma("unroll") for (int ii = 0; ii < 4; ++ii) \
    _Pragma("unroll") for (int jj = 0; jj < 4; ++jj) \
        acc[(mh)*4 + ii][jj] = __builtin_amdgcn_mfma_f32_16x16x32_bf16( \
            av[ii], bv[jj], acc[(mh)*4 + ii][jj], 0, 0, 0); }

    floatx4 acc[8][4];
#pragma unroll
    for (int i = 0; i < 8; ++i)
#pragma unroll
        for (int j = 0; j < 4; ++j)
            acc[i][j] = floatx4{0.f, 0.f, 0.f, 0.f};

    const int NT = K >> 6;

    // ---- prologue: stage tile 0 into buf 0 (issue order Ah0,Bh0,Ah1,Bh1)
    STAGE_A(0, 0, 0, 0); STAGE_A(0, 0, 1, 0);
    STAGE_B(0, 0, 0, 0); STAGE_B(0, 0, 1, 0);
    STAGE_A(0, 1, 0, 0); STAGE_A(0, 1, 1, 0);
    STAGE_B(0, 1, 0, 0); STAGE_B(0, 1, 1, 0);
    VMW(4);               // h0 of tile 0 landed; h1 (4 loads) still in flight
    GB; SB0;

    for (int t = 0; t < NT - 1; ++t) {
        const int b   = t & 1;
        const int nb  = b ^ 1;
        const int kt1 = (t + 1) << 6;
        short8 av[4], bv[4];
        // P0: ks=0, m-half 0 ; prefetch A-h0 of t+1
        LDA4(b, 0, 0, av); LDB4(b, 0, bv);
        STAGE_A(kt1, 0, 0, nb); STAGE_A(kt1, 0, 1, nb);
        GB; LGKM0; SB0;
        __builtin_amdgcn_s_setprio(1); MFMA16(0, av, bv); __builtin_amdgcn_s_setprio(0);
        GB;
        // P1: ks=0, m-half 1 (reuse bv) ; prefetch B-h0 of t+1
        LDA4(b, 0, 1, av);
        STAGE_B(kt1, 0, 0, nb); STAGE_B(kt1, 0, 1, nb);
        GB; LGKM0; SB0;
        __builtin_amdgcn_s_setprio(1); MFMA16(1, av, bv); __builtin_amdgcn_s_setprio(0);
        VMW(4);           // drain h1 of tile t; h0 of t+1 stays in flight
        GB;
        // P2: ks=1, m-half 0 ; prefetch A-h1 of t+1
        LDA4(b, 1, 0, av); LDB4(b, 1, bv);
        STAGE_A(kt1, 1, 0, nb); STAGE_A(kt1, 1, 1, nb);
        GB; LGKM0; SB0;
        __builtin_amdgcn_s_setprio(1); MFMA16(0, av, bv); __builtin_amdgcn_s_setprio(0);
        GB;
        // P3: ks=1, m-half 1 ; prefetch B-h1 of t+1
        LDA4(b, 1, 1, av);
        STAGE_B(kt1, 1, 0, nb); STAGE_B(kt1, 1, 1, nb);
        GB; LGKM0; SB0;
        __builtin_amdgcn_s_setprio(1); MFMA16(1, av, bv); __builtin_amdgcn_s_setprio(0);
        VMW(4);           // drain h0 of t+1; h1 of t+1 stays in flight
        GB;
    }
    // ---- peeled last tile (no prefetch; epilogue drain)
    {
        const int b = (NT - 1) & 1;
        short8 av[4], bv[4];
        LDA4(b, 0, 0, av); LDB4(b, 0, bv);
        GB; LGKM0; SB0;
        __builtin_amdgcn_s_setprio(1); MFMA16(0, av, bv); __builtin_amdgcn_s_setprio(0);
        GB;
        LDA4(b, 0, 1, av);
        GB; LGKM0; SB0;
        __builtin_amdgcn_s_setprio(1); MFMA16(1, av, bv); __builtin_amdgcn_s_setprio(0);
        VMW(0);           // drain h1 of last tile
        GB;
        LDA4(b, 1, 0, av); LDB4(b, 1, bv);
        GB; LGKM0; SB0;
        __builtin_amdgcn_s_setprio(1); MFMA16(0, av, bv); __builtin_amdgcn_s_setprio(0);
        GB;
        LDA4(b, 1, 1, av);
        LGKM0; SB0;
        __builtin_amdgcn_s_setprio(1); MFMA16(1, av, bv); __builtin_amdgcn_s_setprio(0);
    }

    // epilogue: C/D layout col = lane&15, row = quad*4 + reg  (m89-verified)
    if (EPI == 0) {
        float* C = (float*)Cv;
#pragma unroll
        for (int i = 0; i < 8; ++i) {
            const int r = m0 + wm + i * 16 + q * 4;
#pragma unroll
            for (int j = 0; j < 4; ++j) {
                const int cn = n0 + wn + j * 16 + s;
#pragma unroll
                for (int tt = 0; tt < 4; ++tt)
                    C[(size_t)(r + tt) * ldc + cn] = acc[i][j][tt];
            }
        }
    } else {
        // paired layout: frag j even = gate, j odd = up, same lanes.
        // output col ci = (n0+wn)/2 + (j>>1)*16 + s
        ushort_t* X = (ushort_t*)Cv;
        const int cb2 = (n0 + wn) >> 1;
#pragma unroll
        for (int i = 0; i < 8; ++i) {
            const int r = m0 + wm + i * 16 + q * 4;
#pragma unroll
            for (int jp = 0; jp < 2; ++jp) {
                const int cn = cb2 + jp * 16 + s;
#pragma unroll
                for (int tt = 0; tt < 4; ++tt) {
                    const float g  = acc[i][2 * jp][tt];
                    const float u  = acc[i][2 * jp + 1][tt];
                    const float sv = g / (1.0f + __expf(-g));
                    X[(size_t)(r + tt) * ldc + cn] = f2bf(sv * u);
                }
            }
        }
    }
#undef STAGE_A
#undef STAGE_B
#undef LDA4
#undef LDB4
#undef MFMA16
}

// =====================================================================
extern "C" void kernel_launch(void* const* d_in, const int* in_sizes, int n_in,
                              void* d_out, int out_size, void* d_ws, size_t ws_size,
                              hipStream_t stream)
{
    const float* hs  = (const float*)d_in[0];  // [32768][2048]
    const float* wgu = (const float*)d_in[1];  // [2048][1536]
    const float* wd  = (const float*)d_in[2];  // [768][2048]
    float*       out = (float*)d_out;          // [32768][2048] fp32

    // workspace layout (bytes): wgu_t | wd_t | x
    char* ws = (char*)d_ws;
    ushort_t* wgu_t = (ushort_t*)ws;                          // [1536][2048] bf16 (gu-paired rows)
    ushort_t* wd_t  = (ushort_t*)(ws + 6291456);              // [2048][768]  bf16
    ushort_t* xb    = (ushort_t*)(ws + 9437184);              // [32768][768] bf16

    // d_out doubles as scratch for bf16 activations (GEMM2 overwrites all of out)
    ushort_t* hs_b = (ushort_t*)d_out;                        // [32768][2048] bf16, 134217728 B

    // 1. cast activations fp32->bf16
    cast_f32_bf16_k<<<32768, 256, 0, stream>>>(hs, hs_b);
    // 2. transpose-cast weights to [N][K] bf16 (wgu with gate/up row pairing)
    transpose_cast_k<true><<<dim3(N1_DIM / 32, H_DIM / 32), dim3(32, 8), 0, stream>>>(
        wgu, wgu_t, H_DIM, N1_DIM);
    transpose_cast_k<false><<<dim3(H_DIM / 32, I_DIM / 32), dim3(32, 8), 0, stream>>>(
        wd, wd_t, I_DIM, H_DIM);
    // 3. GEMM1 (+fused SiLU*mul): x = silu(gate)*up, written directly as bf16 [32768][768]
    gemm_bt8<1><<<(T_TOK / 256) * (N1_DIM / 256), 512, 0, stream>>>(
        hs_b, wgu_t, (void*)xb, H_DIM, H_DIM, I_DIM, H_DIM);
    // 4. GEMM2: out = x @ Wd   [32768][2048] fp32
    gemm_bt8<0><<<(T_TOK / 256) * (H_DIM / 256), 512, 0, stream>>>(
        xb, wd_t, (void*)out, I_DIM, I_DIM, H_DIM, I_DIM);
}

// Round 2
// 716.347 us; speedup vs baseline: 1.2435x; 1.0446x over previous
//
#include <hip/hip_runtime.h>

// Problem constants: T=32768 tokens, H=2048 hidden, I=768 intermediate
#define T_TOK 32768
#define H_DIM 2048
#define I_DIM 768
#define N1_DIM 1536   // 2*I

typedef unsigned short ushort_t;
typedef __attribute__((ext_vector_type(8))) short  short8;   // 8 bf16 = 4 VGPRs (MFMA A/B frag)
typedef __attribute__((ext_vector_type(4))) float  floatx4;  // MFMA C/D frag

// ---- bf16 helpers (raw-bit, RNE) ----
__device__ __forceinline__ ushort_t f2bf(float f) {
    union { float f; unsigned u; } v; v.f = f;
    unsigned u = v.u;
    unsigned r = (u + 0x7fffu + ((u >> 16) & 1u)) >> 16;
    return (ushort_t)r;
}

// ---- async global->LDS, 16B per lane (dest = wave-uniform base + lane*16) ----
typedef __attribute__((address_space(1))) const void gq_t;
typedef __attribute__((address_space(3))) void lq_t;
__device__ __forceinline__ void gld_lds16(const void* g, void* l) {
    __builtin_amdgcn_global_load_lds((gq_t*)g, (lq_t*)l, 16, 0, 0);
}

// =====================================================================
// cast fp32 -> bf16, 8 elems/thread (grid*256*8 == n exactly)
// =====================================================================
__global__ __launch_bounds__(256) void cast_f32_bf16_k(
    const float* __restrict__ in, ushort_t* __restrict__ out)
{
    size_t i = ((size_t)blockIdx.x * 256 + threadIdx.x) * 8;
    const float4 a = *(const float4*)(in + i);
    const float4 b = *(const float4*)(in + i + 4);
    short8 o;
    o[0] = (short)f2bf(a.x); o[1] = (short)f2bf(a.y);
    o[2] = (short)f2bf(a.z); o[3] = (short)f2bf(a.w);
    o[4] = (short)f2bf(b.x); o[5] = (short)f2bf(b.y);
    o[6] = (short)f2bf(b.z); o[7] = (short)f2bf(b.w);
    *(short8*)(out + i) = o;
}

// =====================================================================
// gate/up pairing permutation for wgu_t rows:
//   source col c (c<768: gate c ; c>=768: up c-768) -> out row
//   pair group of 32 rows = [16 gate cols | 16 up cols] for the same ci range.
// =====================================================================
__device__ __forceinline__ int gu_perm(int c) {
    const int t  = (c >= I_DIM) ? 1 : 0;
    const int cc = c - t * I_DIM;
    return ((cc >> 4) << 5) + (t << 4) + (cc & 15);
}

// =====================================================================
// transpose + cast: in fp32 [R][C] -> out bf16 [perm(C)][R]  (R,C mult of 32)
// =====================================================================
template <bool PERM>
__global__ __launch_bounds__(256) void transpose_cast_k(
    const float* __restrict__ in, ushort_t* __restrict__ out, int R, int C)
{
    __shared__ float tile[32][33];
    const int c0 = blockIdx.x * 32;
    const int r0 = blockIdx.y * 32;
    const int tx = threadIdx.x;   // 0..31
    const int ty = threadIdx.y;   // 0..7
#pragma unroll
    for (int dy = 0; dy < 32; dy += 8)
        tile[ty + dy][tx] = in[(size_t)(r0 + ty + dy) * C + (c0 + tx)];
    __syncthreads();
#pragma unroll
    for (int dy = 0; dy < 32; dy += 8) {
        const int c = c0 + ty + dy;
        const int orow = PERM ? gu_perm(c) : c;
        out[(size_t)orow * R + (r0 + tx)] = f2bf(tile[tx][ty + dy]);
    }
}

// =====================================================================
// bf16 GEMM, C = A @ Bt^T — 256x256 tile, BK=64, 512 thr (8 waves, 2Mx4N),
// double-buffered 128 KiB LDS, 4-phase/K-tile schedule, counted vmcnt
// (T3+T4), setprio around MFMA (T5), bijective XCD swizzle + n-fastest
// block decomposition (T1).
//
// LDS layout (ushort idx): A[buf][256 rows][64 k] at 0, B at +32768.
// XOR-swizzled 8-elem k-groups (T2, zero-conflict scheme from the 128^2
// kernel): element (r, kgroup g) stored at slot (g ^ (r&7)).
//   frag read byte addr = r*128 + ((ks*4+q)^(r&7))*16 -> per q-group the
//   XOR spans all 8 slots, 2 lanes/bank = free.
// Staging: chunk = 8 rows x 64 k = 64 lanes x 16B, LINEAR LDS dest;
// swizzle applied on the per-lane GLOBAL k-offset: k = ((lane&7)^(lane>>3))*8
// (both-sides-or-neither, rule #21).
// Stage issue order per tile: P0 A-mh0(2), P1 B(2), P2 B(2), P3 A-mh1(2);
// vmcnt(2) at end of P0 (drains cur A-mh1) and end of P3 (drains next
// A-mh0 + B), never 0 in the main loop.
//
// EPI==0: fp32 C store.  EPI==1: paired gate/up -> x = silu(g)*u, bf16.
// =====================================================================
#define GB    __builtin_amdgcn_s_barrier()
#define SB0   __builtin_amdgcn_sched_barrier(0)
#define LGKM0 asm volatile("s_waitcnt lgkmcnt(0)" ::: "memory")
#define VMW(N) asm volatile("s_waitcnt vmcnt(" #N ")" ::: "memory")

template <int EPI, int NBN>
__global__ __launch_bounds__(512, 2) void gemm_bt8(
    const ushort_t* __restrict__ A,
    const ushort_t* __restrict__ Bt,
    void* __restrict__ Cv,
    int lda, int ldb, int ldc, int K)
{
    __shared__ __align__(16) ushort_t lds[65536];   // 128 KiB

    const int tid  = threadIdx.x;
    const int lane = tid & 63;
    const int wave = tid >> 6;
    const int wm   = (wave >> 2) * 128;   // wave origin rows within tile
    const int wn   = (wave & 3) * 64;     // wave origin cols within tile
    const int s    = lane & 15;
    const int q    = lane >> 4;
    const int s7   = s & 7;

    // bijective XCD swizzle (gridDim.x % 8 == 0), then n-fastest decompose:
    // blocks sharing an A-panel sit adjacently on one XCD -> L2 A reuse.
    const int nwg = gridDim.x;
    const int cpx = nwg >> 3;
    const int wg  = blockIdx.x;
    const int swz = (wg & 7) * cpx + (wg >> 3);
    const int mb  = swz / NBN;            // compile-time NBN -> magic mul
    const int m0  = mb * 256;
    const int n0  = (swz - mb * NBN) * 256;

    // staging: lane -> (row3 = lane>>3, slot = lane&7), global kgroup = slot^row3
    const int r3 = lane >> 3;
    const int sk = ((lane & 7) ^ r3) * 8;
    const ushort_t* Ab = A  + (size_t)(m0 + wave * 8 + r3) * lda + sk;
    const ushort_t* Bb = Bt + (size_t)(n0 + wave * 8 + r3) * ldb + sk;

    // chunk ca = wave + ofs; A: ofs {0,16} = rows [0,64)u[128,192) (mh0),
    //                           ofs {8,24} = rows [64,128)u[192,256) (mh1)
#define STAGE_A(kt, ofs, b) gld_lds16(Ab + (size_t)((ofs) * 8) * lda + (kt), \
                                      &lds[(b) * 16384 + (wave + (ofs)) * 512])
#define STAGE_B(kt, ofs, b) gld_lds16(Bb + (size_t)((ofs) * 8) * ldb + (kt), \
                                      &lds[32768 + (b) * 16384 + (wave + (ofs)) * 512])

    const int arow = wm + s;
    const int brow = wn + s;
#define LDA4(b, ks, mh, av) { _Pragma("unroll") for (int ii = 0; ii < 4; ++ii) \
    av[ii] = *(const short8*)&lds[(b) * 16384 + (arow + (mh) * 64 + ii * 16) * 64 \
                                  + (((ks) * 4 + q) ^ s7) * 8]; }
#define LDB4(b, ks, bv) { _Pragma("unroll") for (int jj = 0; jj < 4; ++jj) \
    bv[jj] = *(const short8*)&lds[32768 + (b) * 16384 + (brow + jj * 16) * 64 \
                                  + (((ks) * 4 + q) ^ s7) * 8]; }
#define MFMA16(mh, av, bv) { _Pragma("unroll") for (int ii = 0; ii < 4; ++ii) \
    _Pragma("unroll") for (int jj = 0; jj < 4; ++jj) \
        acc[(mh) * 4 + ii][jj] = __builtin_amdgcn_mfma_f32_16x16x32_bf16( \
            av[ii], bv[jj], acc[(mh) * 4 + ii][jj], 0, 0, 0); }

    floatx4 acc[8][4];
#pragma unroll
    for (int i = 0; i < 8; ++i)
#pragma unroll
        for (int j = 0; j < 4; ++j)
            acc[i][j] = floatx4{0.f, 0.f, 0.f, 0.f};

    const int NT = K >> 6;

    // ---- prologue: stage tile 0 into buf 0; order A-mh0, B*4, A-mh1
    STAGE_A(0, 0, 0);  STAGE_A(0, 16, 0);
    STAGE_B(0, 0, 0);  STAGE_B(0, 8, 0);
    STAGE_B(0, 16, 0); STAGE_B(0, 24, 0);
    STAGE_A(0, 8, 0);  STAGE_A(0, 24, 0);
    VMW(2);               // A-mh0 + B landed; A-mh1 (2 loads) still in flight
    GB; SB0;

    for (int t = 0; t < NT - 1; ++t) {
        const int b   = t & 1;
        const int nb  = b ^ 1;
        const int kt1 = (t + 1) << 6;
        short8 av[4], bv[4];
        // P0: ks=0, m-half 0 ; prefetch A-mh0 of t+1
        LDA4(b, 0, 0, av); LDB4(b, 0, bv);
        STAGE_A(kt1, 0, nb); STAGE_A(kt1, 16, nb);
        GB; LGKM0; SB0;
        __builtin_amdgcn_s_setprio(1); MFMA16(0, av, bv); __builtin_amdgcn_s_setprio(0);
        VMW(2);           // drain A-mh1 of tile t (needed by P1); keep t+1 A-mh0
        GB;
        // P1: ks=0, m-half 1 (reuse bv) ; prefetch B of t+1 (1st half)
        LDA4(b, 0, 1, av);
        STAGE_B(kt1, 0, nb); STAGE_B(kt1, 8, nb);
        GB; LGKM0; SB0;
        __builtin_amdgcn_s_setprio(1); MFMA16(1, av, bv); __builtin_amdgcn_s_setprio(0);
        GB;
        // P2: ks=1, m-half 0 ; prefetch B of t+1 (2nd half)
        LDA4(b, 1, 0, av); LDB4(b, 1, bv);
        STAGE_B(kt1, 16, nb); STAGE_B(kt1, 24, nb);
        GB; LGKM0; SB0;
        __builtin_amdgcn_s_setprio(1); MFMA16(0, av, bv); __builtin_amdgcn_s_setprio(0);
        GB;
        // P3: ks=1, m-half 1 ; prefetch A-mh1 of t+1
        LDA4(b, 1, 1, av);
        STAGE_A(kt1, 8, nb); STAGE_A(kt1, 24, nb);
        GB; LGKM0; SB0;
        __builtin_amdgcn_s_setprio(1); MFMA16(1, av, bv); __builtin_amdgcn_s_setprio(0);
        VMW(2);           // drain A-mh0 + B of t+1 (needed by next P0); keep A-mh1
        GB;
    }
    // ---- peeled last tile (no prefetch)
    {
        const int b = (NT - 1) & 1;
        short8 av[4], bv[4];
        LDA4(b, 0, 0, av); LDB4(b, 0, bv);
        GB; LGKM0; SB0;
        __builtin_amdgcn_s_setprio(1); MFMA16(0, av, bv); __builtin_amdgcn_s_setprio(0);
        VMW(0);           // drain A-mh1 of last tile
        GB;
        LDA4(b, 0, 1, av);
        GB; LGKM0; SB0;
        __builtin_amdgcn_s_setprio(1); MFMA16(1, av, bv); __builtin_amdgcn_s_setprio(0);
        GB;
        LDA4(b, 1, 0, av); LDB4(b, 1, bv);
        GB; LGKM0; SB0;
        __builtin_amdgcn_s_setprio(1); MFMA16(0, av, bv); __builtin_amdgcn_s_setprio(0);
        GB;
        LDA4(b, 1, 1, av);
        LGKM0; SB0;
        __builtin_amdgcn_s_setprio(1); MFMA16(1, av, bv); __builtin_amdgcn_s_setprio(0);
    }

    // epilogue: C/D layout col = lane&15, row = quad*4 + reg  (m89-verified)
    if (EPI == 0) {
        float* C = (float*)Cv;
#pragma unroll
        for (int i = 0; i < 8; ++i) {
            const int r = m0 + wm + i * 16 + q * 4;
#pragma unroll
            for (int j = 0; j < 4; ++j) {
                const int cn = n0 + wn + j * 16 + s;
#pragma unroll
                for (int tt = 0; tt < 4; ++tt)
                    C[(size_t)(r + tt) * ldc + cn] = acc[i][j][tt];
            }
        }
    } else {
        // paired layout: frag j even = gate, j odd = up, same lanes.
        // output col ci = (n0+wn)/2 + (j>>1)*16 + s
        ushort_t* X = (ushort_t*)Cv;
        const int cb2 = (n0 + wn) >> 1;
#pragma unroll
        for (int i = 0; i < 8; ++i) {
            const int r = m0 + wm + i * 16 + q * 4;
#pragma unroll
            for (int jp = 0; jp < 2; ++jp) {
                const int cn = cb2 + jp * 16 + s;
#pragma unroll
                for (int tt = 0; tt < 4; ++tt) {
                    const float g  = acc[i][2 * jp][tt];
                    const float u  = acc[i][2 * jp + 1][tt];
                    const float sv = g / (1.0f + __expf(-g));
                    X[(size_t)(r + tt) * ldc + cn] = f2bf(sv * u);
                }
            }
        }
    }
#undef STAGE_A
#undef STAGE_B
#undef LDA4
#undef LDB4
#undef MFMA16
}

// =====================================================================
extern "C" void kernel_launch(void* const* d_in, const int* in_sizes, int n_in,
                              void* d_out, int out_size, void* d_ws, size_t ws_size,
                              hipStream_t stream)
{
    const float* hs  = (const float*)d_in[0];  // [32768][2048]
    const float* wgu = (const float*)d_in[1];  // [2048][1536]
    const float* wd  = (const float*)d_in[2];  // [768][2048]
    float*       out = (float*)d_out;          // [32768][2048] fp32

    // workspace layout (bytes): wgu_t | wd_t | x
    char* ws = (char*)d_ws;
    ushort_t* wgu_t = (ushort_t*)ws;                          // [1536][2048] bf16 (gu-paired rows)
    ushort_t* wd_t  = (ushort_t*)(ws + 6291456);              // [2048][768]  bf16
    ushort_t* xb    = (ushort_t*)(ws + 9437184);              // [32768][768] bf16

    // d_out doubles as scratch for bf16 activations (GEMM2 overwrites all of out)
    ushort_t* hs_b = (ushort_t*)d_out;                        // [32768][2048] bf16, 134217728 B

    // 1. cast activations fp32->bf16
    cast_f32_bf16_k<<<32768, 256, 0, stream>>>(hs, hs_b);
    // 2. transpose-cast weights to [N][K] bf16 (wgu with gate/up row pairing)
    transpose_cast_k<true><<<dim3(N1_DIM / 32, H_DIM / 32), dim3(32, 8), 0, stream>>>(
        wgu, wgu_t, H_DIM, N1_DIM);
    transpose_cast_k<false><<<dim3(H_DIM / 32, I_DIM / 32), dim3(32, 8), 0, stream>>>(
        wd, wd_t, I_DIM, H_DIM);
    // 3. GEMM1 (+fused SiLU*mul): x = silu(gate)*up, written directly as bf16 [32768][768]
    gemm_bt8<1, 6><<<(T_TOK / 256) * (N1_DIM / 256), 512, 0, stream>>>(
        hs_b, wgu_t, (void*)xb, H_DIM, H_DIM, I_DIM, H_DIM);
    // 4. GEMM2: out = x @ Wd   [32768][2048] fp32
    gemm_bt8<0, 8><<<(T_TOK / 256) * (H_DIM / 256), 512, 0, stream>>>(
        xb, wd_t, (void*)out, I_DIM, I_DIM, H_DIM, I_DIM);
}